// Round 17
// baseline (154.503 us; speedup 1.0000x reference)
//
#include <hip/hip_runtime.h>
#include <hip/hip_fp16.h>

#define FDIM 128
#define FCLS 40
#define EPB  8192      // edges per binning block
#define BSH  8         // bucket shift: 256 nodes per bucket
#define BKN  (1 << BSH)
#define LCAP 2560      // staged edges per agg block (64 nodes, mean 1024, sd 32)

typedef short s16x8 __attribute__((ext_vector_type(8)));   // 8 bf16 (4 VGPRs)
typedef float f32x4 __attribute__((ext_vector_type(4)));   // MFMA accumulator
typedef int   i32x4 __attribute__((ext_vector_type(4)));   // 16B nt-store carrier

// ---- bf16 helpers (bit-level, RNE) ----------------------------------------
__device__ __forceinline__ float bf2f(unsigned short u) {
    union { unsigned int i; float f; } v; v.i = ((unsigned int)u) << 16; return v.f;
}
__device__ __forceinline__ unsigned short f2bf(float f) {
    union { float f; unsigned int i; } v; v.f = f;
    unsigned int u = v.i + 0x7FFFu + ((v.i >> 16) & 1u);   // round-nearest-even
    return (unsigned short)(u >> 16);
}

// ---------------------------------------------------------------------------
// Fused prep: blocks [0,nblkA) = per-block LDS histogram of dst>>BSH;
// blocks [nblkA, nblkA+19) = weight packing into MFMA B-fragment order.
// ---------------------------------------------------------------------------
__global__ __launch_bounds__(256) void prep_hist_pack(const int* __restrict__ dst,
                                                      int* __restrict__ hist,
                                                      int E, int nblkA, int NB,
                                                      const float* __restrict__ W1,
                                                      const float* __restrict__ W2,
                                                      const float* __restrict__ Wc,
                                                      unsigned short* __restrict__ Wp1,
                                                      unsigned short* __restrict__ Wp2,
                                                      unsigned short* __restrict__ Wpc) {
    int t = threadIdx.x;
    if ((int)blockIdx.x < nblkA) {
        __shared__ int h[BKN];
        h[t] = 0;
        __syncthreads();
        int base = blockIdx.x * EPB;
        int end = min(base + EPB, E);
        for (int i = base + t; i < end; i += 256) atomicAdd(&h[dst[i] >> BSH], 1);
        __syncthreads();
        for (int i = t; i < NB; i += 256) hist[i * nblkA + blockIdx.x] = h[i];
    } else {
        int blk = blockIdx.x - nblkA;
        const float* W; unsigned short* Wp; int ncols, ct;
        if (blk < 8)       { W = W1; Wp = Wp1; ncols = FDIM; ct = blk; }
        else if (blk < 16) { W = W2; Wp = Wp2; ncols = FDIM; ct = blk - 8; }
        else               { W = Wc; Wp = Wpc; ncols = FCLS; ct = blk - 16; }
        int tt = ct * 256 + t;
        int lane = tt & 63, ks = (tt >> 6) & 3;
        int n  = ct * 16 + (lane & 15);
        int kb = ks * 32 + (lane >> 4) * 8;
        unsigned short v[8];
#pragma unroll
        for (int j = 0; j < 8; ++j) {
            v[j] = (n < ncols) ? f2bf(W[(size_t)(kb + j) * ncols + n]) : (unsigned short)0;
        }
        ushort4* o = (ushort4*)(Wp + (size_t)tt * 8);
        o[0] = ushort4{v[0], v[1], v[2], v[3]};
        o[1] = ushort4{v[4], v[5], v[6], v[7]};
    }
}

// ---- hierarchical exclusive scan of hist[n] (in-place), 1024 elems/block ----
__global__ __launch_bounds__(256) void hscan_partial(const int* __restrict__ data,
                                                     int* __restrict__ bsums, int n) {
    __shared__ int s[256];
    int t = threadIdx.x;
    int base = blockIdx.x * 1024 + t * 4;
    int v = 0;
#pragma unroll
    for (int j = 0; j < 4; ++j) if (base + j < n) v += data[base + j];
    s[t] = v;
    __syncthreads();
    for (int off = 128; off > 0; off >>= 1) {
        if (t < off) s[t] += s[t + off];
        __syncthreads();
    }
    if (t == 0) bsums[blockIdx.x] = s[0];
}

// final scan; each block derives its own base by reducing bsums[0..blockIdx)
__global__ __launch_bounds__(256) void hscan_final(int* __restrict__ data,
                                                   const int* __restrict__ bsums,
                                                   int n, int nb) {
    __shared__ int s[256];
    int t = threadIdx.x;
    s[t] = (t < nb && t < (int)blockIdx.x) ? bsums[t] : 0;
    __syncthreads();
    for (int off = 128; off > 0; off >>= 1) {
        if (t < off) s[t] += s[t + off];
        __syncthreads();
    }
    int base = s[0];
    __syncthreads();

    int idx = blockIdx.x * 1024 + t * 4;
    int v[4];
    int sum = 0;
#pragma unroll
    for (int j = 0; j < 4; ++j) {
        v[j] = (idx + j < n) ? data[idx + j] : 0;
        sum += v[j];
    }
    s[t] = sum;
    __syncthreads();
    for (int off = 1; off < 256; off <<= 1) {
        int x = 0;
        if (t >= off) x = s[t - off];
        __syncthreads();
        s[t] += x;
        __syncthreads();
    }
    int running = base + s[t] - sum;                 // exclusive prefix
#pragma unroll
    for (int j = 0; j < 4; ++j) {
        if (idx + j < n) data[idx + j] = running;
        running += v[j];
    }
}

// ---------------------------------------------------------------------------
// Fused: blocks [0,nblkA) = bin_scatter (CSR critical path);
//        blocks [nblkA, nblkA+gemmBlocks) = layer-1 GEMM (independent work).
// ---------------------------------------------------------------------------
__global__ __launch_bounds__(256) void binscatter_gemm1(const int* __restrict__ src,
                                                        const int* __restrict__ dst,
                                                        const int* __restrict__ histS,
                                                        unsigned int* __restrict__ binnedPk,
                                                        int E, int nblkA, int NB,
                                                        const float* __restrict__ A,
                                                        const unsigned short* __restrict__ Wp,
                                                        unsigned short* __restrict__ C, int M) {
    int t = threadIdx.x;
    if ((int)blockIdx.x < nblkA) {
        // ---- bin_scatter part ----
        __shared__ int cur[BKN];
        for (int i = t; i < NB; i += 256) cur[i] = histS[i * nblkA + blockIdx.x];
        __syncthreads();
        int base = blockIdx.x * EPB;
        int end = min(base + EPB, E);
        for (int i = base + t; i < end; i += 256) {
            int d = dst[i];
            int pos = atomicAdd(&cur[d >> BSH], 1);     // LDS atomic
            binnedPk[pos] = (unsigned int)(src[i] & 0xFFFF) | ((unsigned int)d << 16);
        }
    } else {
        // ---- layer-1 GEMM part: C(quarter-blocked bf16) = A(f32) @ Wp ----
        int wave = t >> 6;
        int lane = t & 63;
        int row0 = (((int)blockIdx.x - nblkA) * 4 + wave) * 16;
        if (row0 >= M) return;
        int m = lane & 15;
        int g = lane >> 4;

        const float4* Arow = (const float4*)(A + (size_t)(row0 + m) * FDIM);
        s16x8 a[4];
#pragma unroll
        for (int ks = 0; ks < 4; ++ks) {
            float4 lo = Arow[ks * 8 + g * 2];
            float4 hi = Arow[ks * 8 + g * 2 + 1];
            s16x8 av;
            av[0] = (short)f2bf(lo.x); av[1] = (short)f2bf(lo.y);
            av[2] = (short)f2bf(lo.z); av[3] = (short)f2bf(lo.w);
            av[4] = (short)f2bf(hi.x); av[5] = (short)f2bf(hi.y);
            av[6] = (short)f2bf(hi.z); av[7] = (short)f2bf(hi.w);
            a[ks] = av;
        }

        for (int ct = 0; ct < 8; ++ct) {
            f32x4 acc = {0.f, 0.f, 0.f, 0.f};
#pragma unroll
            for (int ks = 0; ks < 4; ++ks) {
                s16x8 b = *(const s16x8*)(Wp + ((size_t)((ct * 4 + ks) * 64 + lane)) * 8);
                acc = __builtin_amdgcn_mfma_f32_16x16x32_bf16(a[ks], b, acc, 0, 0, 0);
            }
            int q  = ct >> 1;
            int cc = (ct & 1) * 16 + m;
            int r0 = row0 + g * 4;
#pragma unroll
            for (int r = 0; r < 4; ++r)
                __builtin_nontemporal_store(f2bf(acc[r]),
                    &C[((size_t)q * M + (r0 + r)) * 32 + cc]);
        }
    }
}

// per-bucket node histogram + in-LDS exclusive scan -> offsets, dinv
__global__ __launch_bounds__(256) void node_hist_scan(const unsigned int* __restrict__ binnedPk,
                                                      const int* __restrict__ histS,
                                                      int* __restrict__ offsets,
                                                      float* __restrict__ dinv,
                                                      int N, int E, int nblkA, int NB) {
    int b = blockIdx.x;
    int node0 = b << BSH;
    int t = threadIdx.x;
    __shared__ int c[BKN];
    c[t] = 0;
    __syncthreads();
    int lo = histS[b * nblkA];
    int hi = (b == NB - 1) ? E : histS[(b + 1) * nblkA];
    for (int i = lo + t; i < hi; i += 256) {
        int d = (int)(binnedPk[i] >> 16);
        atomicAdd(&c[d - node0], 1);                // LDS atomic
    }
    __syncthreads();
    int v = c[t];
    for (int off = 1; off < 256; off <<= 1) {
        int x = (t >= off) ? c[t - off] : 0;
        __syncthreads();
        c[t] += x;
        __syncthreads();
    }
    int excl = lo + c[t] - v;                       // bucket base + exclusive prefix
    int idx = node0 + t;
    if (idx < N) {
        offsets[idx] = excl;
        dinv[idx] = rsqrtf((float)v + 1.0f);
        if (idx == N - 1) offsets[N] = excl + v;    // == E
    }
}

// per-bucket exact positions; writes srcPk = src | fp16(dinv[s]*dinv[d])<<16
__global__ __launch_bounds__(256) void csr_scatter(const unsigned int* __restrict__ binnedPk,
                                                   const int* __restrict__ offsets,
                                                   const float* __restrict__ dinv,
                                                   unsigned int* __restrict__ srcPk, int N) {
    int b = blockIdx.x;
    int node0 = b << BSH;
    int node1 = min(node0 + BKN, N);
    __shared__ int cur[BKN];
    int t = threadIdx.x;
    if (node0 + t < node1) cur[t] = offsets[node0 + t];
    __syncthreads();
    int lo = offsets[node0];
    int hi = offsets[node1];
    for (int i = lo + t; i < hi; i += 256) {
        unsigned int p = binnedPk[i];
        int s = (int)(p & 0xFFFFu);
        int d = (int)(p >> 16);
        int pos = atomicAdd(&cur[d - node0], 1);    // LDS atomic
        float coef = dinv[s] * dinv[d];
        unsigned short cb = __half_as_ushort(__float2half(coef));
        srcPk[pos] = (unsigned int)s | ((unsigned int)cb << 16);
    }
}

// ---------------------------------------------------------------------------
// Quarter-blocked bf16 layout: buf[q][node][32 cols], q = col/32.
// ---------------------------------------------------------------------------

// quarter-blocked bf16 A variant (layer 2)
__global__ __launch_bounds__(256) void gemm_mfma(const unsigned short* __restrict__ A,
                                                 const unsigned short* __restrict__ Wp,
                                                 unsigned short* __restrict__ C, int M) {
    int wave = threadIdx.x >> 6;
    int lane = threadIdx.x & 63;
    int row0 = (blockIdx.x * 4 + wave) * 16;
    if (row0 >= M) return;
    int m = lane & 15;
    int g = lane >> 4;

    const s16x8* A8 = (const s16x8*)A;
    s16x8 a[4];
#pragma unroll
    for (int ks = 0; ks < 4; ++ks)
        a[ks] = A8[((size_t)ks * M + (row0 + m)) * 4 + g];

    for (int ct = 0; ct < 8; ++ct) {
        f32x4 acc = {0.f, 0.f, 0.f, 0.f};
#pragma unroll
        for (int ks = 0; ks < 4; ++ks) {
            s16x8 b = *(const s16x8*)(Wp + ((size_t)((ct * 4 + ks) * 64 + lane)) * 8);
            acc = __builtin_amdgcn_mfma_f32_16x16x32_bf16(a[ks], b, acc, 0, 0, 0);
        }
        int q  = ct >> 1;
        int cc = (ct & 1) * 16 + m;
        int r0 = row0 + g * 4;
#pragma unroll
        for (int r = 0; r < 4; ++r)
            __builtin_nontemporal_store(f2bf(acc[r]),
                &C[((size_t)q * M + (r0 + r)) * 32 + cc]);
    }
}

// out[M,40](f32) = A(quarter-blocked bf16) @ Wc(packed, zero-padded) + bc
__global__ __launch_bounds__(256) void classifier_mfma(const unsigned short* __restrict__ A,
                                                       const unsigned short* __restrict__ Wp,
                                                       const float* __restrict__ bc,
                                                       float* __restrict__ out, int M) {
    int wave = threadIdx.x >> 6;
    int lane = threadIdx.x & 63;
    int row0 = (blockIdx.x * 4 + wave) * 16;
    if (row0 >= M) return;
    int m = lane & 15;
    int g = lane >> 4;

    const s16x8* A8 = (const s16x8*)A;
    s16x8 a[4];
#pragma unroll
    for (int ks = 0; ks < 4; ++ks)
        a[ks] = A8[((size_t)ks * M + (row0 + m)) * 4 + g];

    for (int ct = 0; ct < 3; ++ct) {
        f32x4 acc = {0.f, 0.f, 0.f, 0.f};
#pragma unroll
        for (int ks = 0; ks < 4; ++ks) {
            s16x8 b = *(const s16x8*)(Wp + ((size_t)((ct * 4 + ks) * 64 + lane)) * 8);
            acc = __builtin_amdgcn_mfma_f32_16x16x32_bf16(a[ks], b, acc, 0, 0, 0);
        }
        int n = ct * 16 + m;
        if (n < FCLS) {
            float bias = bc[n];
            int r0 = row0 + g * 4;
#pragma unroll
            for (int r = 0; r < 4; ++r)
                __builtin_nontemporal_store(acc[r] + bias,
                    &out[(size_t)(r0 + r) * FCLS + n]);
        }
    }
}

// ---------------------------------------------------------------------------
// Fused aggregation over quarter-blocked H with XCD-pinned quarters and
// LDS-staged metadata; software-pipelined depth 6. NEW: output stores and
// metadata staging loads are NON-TEMPORAL, so the gather-hot input quarter
// (3.2 MB) stays resident in the XCD-pair's L2 instead of being evicted by
// write-allocate / metadata lines.
// ---------------------------------------------------------------------------
__global__ __launch_bounds__(256) void agg_fused(const unsigned short* __restrict__ H,
                                                 const float* __restrict__ dinv,
                                                 const float* __restrict__ bias,
                                                 const unsigned int* __restrict__ srcPk,
                                                 const int* __restrict__ offsets,
                                                 unsigned short* __restrict__ OUT,
                                                 int N, int bpq) {
    __shared__ unsigned int eLds[LCAP];
    int gid = blockIdx.x;
    int q = (gid >> 1) & 3;                        // (gid % 8) >> 1
    int b = (gid >> 3) * 2 + (gid & 1);            // within-quarter block
    int t = threadIdx.x;
    int nodeB = b * 64;
    int nodeE = min(nodeB + 64, N);
    int node = nodeB + (t >> 2);
    bool valid = node < N;
    int c4 = t & 3;

    int lo  = offsets[nodeB];
    int cnt = offsets[nodeE] - lo;
    int stg = min(cnt, LCAP);
    for (int i = t; i < stg; i += 256)
        eLds[i] = __builtin_nontemporal_load(&srcPk[lo + i]);
    __syncthreads();

    const s16x8* H8 = (const s16x8*)H;             // quarter-row = 4 s16x8
    size_t qbase = (size_t)q * N * 4;

    float di = 0.f, d2 = 0.f;
    int e = 0, end = 0;
    float acc[8];
#pragma unroll
    for (int j = 0; j < 8; ++j) acc[j] = 0.f;
    if (valid) {
        di = dinv[node];
        d2 = di * di;
        e   = offsets[node] - lo;
        end = offsets[node + 1] - lo;
        s16x8 h = H8[qbase + (size_t)node * 4 + c4];
#pragma unroll
        for (int j = 0; j < 8; ++j) acc[j] = bf2f((unsigned short)h[j]) * d2;
    }

    if (cnt <= LCAP) {
        if (valid) {
            if (e + 6 <= end) {
                unsigned int p[6];
#pragma unroll
                for (int k = 0; k < 6; ++k) p[k] = eLds[e + k];
                while (e + 12 <= end) {
                    s16x8 av[6];
#pragma unroll
                    for (int k = 0; k < 6; ++k)
                        av[k] = H8[qbase + (size_t)(p[k] & 0xFFFFu) * 4 + c4];
                    unsigned int pn[6];
#pragma unroll
                    for (int k = 0; k < 6; ++k) pn[k] = eLds[e + 6 + k];
#pragma unroll
                    for (int k = 0; k < 6; ++k) {
                        float cf = __half2float(__ushort_as_half((unsigned short)(p[k] >> 16)));
#pragma unroll
                        for (int j = 0; j < 8; ++j)
                            acc[j] = fmaf(bf2f((unsigned short)av[k][j]), cf, acc[j]);
                    }
#pragma unroll
                    for (int k = 0; k < 6; ++k) p[k] = pn[k];
                    e += 6;
                }
                s16x8 av[6];
#pragma unroll
                for (int k = 0; k < 6; ++k)
                    av[k] = H8[qbase + (size_t)(p[k] & 0xFFFFu) * 4 + c4];
#pragma unroll
                for (int k = 0; k < 6; ++k) {
                    float cf = __half2float(__ushort_as_half((unsigned short)(p[k] >> 16)));
#pragma unroll
                    for (int j = 0; j < 8; ++j)
                        acc[j] = fmaf(bf2f((unsigned short)av[k][j]), cf, acc[j]);
                }
                e += 6;
            }
            for (; e + 2 <= end; e += 2) {
                unsigned int p0 = eLds[e], p1 = eLds[e + 1];
                s16x8 a0 = H8[qbase + (size_t)(p0 & 0xFFFFu) * 4 + c4];
                s16x8 a1 = H8[qbase + (size_t)(p1 & 0xFFFFu) * 4 + c4];
                float c0 = __half2float(__ushort_as_half((unsigned short)(p0 >> 16)));
                float c1 = __half2float(__ushort_as_half((unsigned short)(p1 >> 16)));
#pragma unroll
                for (int j = 0; j < 8; ++j) {
                    acc[j] = fmaf(bf2f((unsigned short)a0[j]), c0, acc[j]);
                    acc[j] = fmaf(bf2f((unsigned short)a1[j]), c1, acc[j]);
                }
            }
            if (e < end) {
                unsigned int p0 = eLds[e];
                float c0 = __half2float(__ushort_as_half((unsigned short)(p0 >> 16)));
                s16x8 a0 = H8[qbase + (size_t)(p0 & 0xFFFFu) * 4 + c4];
#pragma unroll
                for (int j = 0; j < 8; ++j)
                    acc[j] = fmaf(bf2f((unsigned short)a0[j]), c0, acc[j]);
            }
        }
    } else {
        if (valid) {
            for (; e + 6 <= end; e += 6) {
                unsigned int p[6];
#pragma unroll
                for (int k = 0; k < 6; ++k) p[k] = srcPk[lo + e + k];
                s16x8 av[6];
#pragma unroll
                for (int k = 0; k < 6; ++k)
                    av[k] = H8[qbase + (size_t)(p[k] & 0xFFFFu) * 4 + c4];
#pragma unroll
                for (int k = 0; k < 6; ++k) {
                    float cf = __half2float(__ushort_as_half((unsigned short)(p[k] >> 16)));
#pragma unroll
                    for (int j = 0; j < 8; ++j)
                        acc[j] = fmaf(bf2f((unsigned short)av[k][j]), cf, acc[j]);
                }
            }
            for (; e < end; ++e) {
                unsigned int p0 = srcPk[lo + e];
                float c0 = __half2float(__ushort_as_half((unsigned short)(p0 >> 16)));
                s16x8 a0 = H8[qbase + (size_t)(p0 & 0xFFFFu) * 4 + c4];
#pragma unroll
                for (int j = 0; j < 8; ++j)
                    acc[j] = fmaf(bf2f((unsigned short)a0[j]), c0, acc[j]);
            }
        }
    }

    if (valid) {
        const float4* bq = (const float4*)(bias + q * 32 + c4 * 8);
        float4 b0 = bq[0], b1 = bq[1];
        float bb[8] = {b0.x, b0.y, b0.z, b0.w, b1.x, b1.y, b1.z, b1.w};
        s16x8 o;
#pragma unroll
        for (int j = 0; j < 8; ++j)
            o[j] = (short)f2bf(fmaxf(acc[j] + bb[j], 0.0f));
        union { s16x8 v; i32x4 u; } cv; cv.v = o;
        __builtin_nontemporal_store(cv.u,
            (i32x4*)&((s16x8*)OUT)[qbase + (size_t)node * 4 + c4]);
    }
}

// ---------------------------------------------------------------------------
extern "C" void kernel_launch(void* const* d_in, const int* in_sizes, int n_in,
                              void* d_out, int out_size, void* d_ws, size_t ws_size,
                              hipStream_t stream) {
    const float* x  = (const float*)d_in[0];
    const int*   ei = (const int*)d_in[1];
    const float* W1 = (const float*)d_in[2];
    const float* b1 = (const float*)d_in[3];
    const float* W2 = (const float*)d_in[4];
    const float* b2 = (const float*)d_in[5];
    const float* Wc = (const float*)d_in[6];
    const float* bc = (const float*)d_in[7];
    float* out = (float*)d_out;

    int N = in_sizes[0] / FDIM;
    int E = in_sizes[1] / 2;
    const int* src = ei;
    const int* dst = ei + E;

    int nblkA = (E + EPB - 1) / EPB;            // 98
    int NB    = (N + BKN - 1) >> BSH;           // 196
    int mfmaBlocks = (N / 16 + 3) / 4;          // 782
    int bpq = (N + 63) / 64;                    // 782 blocks per quarter
    int aggBlocks = 4 * bpq;                    // 3128 (divisible by 8)
    int histN = NB * nblkA;                     // 19208
    int hscanBlocks = (histN + 1023) / 1024;    // 19 (<= 256 required)

    // workspace layout:
    // binnedPk[E] | srcPk[E] | offsets[N+1] | hist[histN] | bsums[256]
    // | dinv[N] | Wp1 | Wp2 | Wpc | Hbuf bf16 | Abuf bf16
    unsigned int* binnedPk = (unsigned int*)d_ws;
    unsigned int* srcPk    = binnedPk + E;
    int*  offsets  = (int*)(srcPk + E);
    int*  hist     = offsets + (N + 1);
    int*  bsums    = hist + histN;
    float* dinv    = (float*)(bsums + 256);
    unsigned short* Wp1 = (unsigned short*)(dinv + N);
    unsigned short* Wp2 = Wp1 + 8 * 4 * 64 * 8;
    unsigned short* Wpc = Wp2 + 8 * 4 * 64 * 8;
    unsigned short* Hbuf = Wpc + 3 * 4 * 64 * 8;
    unsigned short* Abuf = Hbuf + (size_t)N * FDIM;

    // ---- prep: bucket histogram + weight packing (1 fused dispatch) ----
    prep_hist_pack<<<nblkA + 19, 256, 0, stream>>>(dst, hist, E, nblkA, NB,
                                                   W1, W2, Wc, Wp1, Wp2, Wpc);
    // ---- CSR build (gemm1 fused into bin_scatter dispatch, off-path) ----
    hscan_partial<<<hscanBlocks, 256, 0, stream>>>(hist, bsums, histN);
    hscan_final<<<hscanBlocks, 256, 0, stream>>>(hist, bsums, histN, hscanBlocks);
    binscatter_gemm1<<<nblkA + mfmaBlocks, 256, 0, stream>>>(src, dst, hist, binnedPk,
                                                             E, nblkA, NB,
                                                             x, Wp1, Hbuf, N);
    node_hist_scan<<<NB, 256, 0, stream>>>(binnedPk, hist, offsets, dinv, N, E, nblkA, NB);
    csr_scatter<<<NB, 256, 0, stream>>>(binnedPk, offsets, dinv, srcPk, N);

    // ---- layer 1 aggregation ----
    agg_fused<<<aggBlocks, 256, 0, stream>>>(Hbuf, dinv, b1, srcPk, offsets, Abuf, N, bpq);

    // ---- layer 2 ----
    gemm_mfma<<<mfmaBlocks, 256, 0, stream>>>(Abuf, Wp2, Hbuf, N);
    agg_fused<<<aggBlocks, 256, 0, stream>>>(Hbuf, dinv, b2, srcPk, offsets, Abuf, N, bpq);

    // ---- classifier ----
    classifier_mfma<<<mfmaBlocks, 256, 0, stream>>>(Abuf, Wpc, bc, out, N);
}

// Round 18
// 130.543 us; speedup vs baseline: 1.1835x; 1.1835x over previous
//
#include <hip/hip_runtime.h>
#include <hip/hip_fp16.h>

#define FDIM 128
#define FCLS 40
#define EPB  4096      // edges per binning block
#define BSH  8         // bucket shift: 256 nodes per bucket
#define BKN  (1 << BSH)
#define LCAP 2560      // staged edges per agg block (64 nodes, mean 1024, sd 32)

typedef short s16x8 __attribute__((ext_vector_type(8)));   // 8 bf16 (4 VGPRs)
typedef float f32x4 __attribute__((ext_vector_type(4)));   // MFMA accumulator

// ---- bf16 helpers (bit-level, RNE) ----------------------------------------
__device__ __forceinline__ float bf2f(unsigned short u) {
    union { unsigned int i; float f; } v; v.i = ((unsigned int)u) << 16; return v.f;
}
__device__ __forceinline__ unsigned short f2bf(float f) {
    union { float f; unsigned int i; } v; v.f = f;
    unsigned int u = v.i + 0x7FFFu + ((v.i >> 16) & 1u);   // round-nearest-even
    return (unsigned short)(u >> 16);
}

// ---------------------------------------------------------------------------
// Fused prep: blocks [0,nblkA) = per-block LDS histogram of dst>>BSH;
// blocks [nblkA, nblkA+19) = weight packing into MFMA B-fragment order.
// ---------------------------------------------------------------------------
__global__ __launch_bounds__(256) void prep_hist_pack(const int* __restrict__ dst,
                                                      int* __restrict__ hist,
                                                      int E, int nblkA, int NB,
                                                      const float* __restrict__ W1,
                                                      const float* __restrict__ W2,
                                                      const float* __restrict__ Wc,
                                                      unsigned short* __restrict__ Wp1,
                                                      unsigned short* __restrict__ Wp2,
                                                      unsigned short* __restrict__ Wpc) {
    int t = threadIdx.x;
    if ((int)blockIdx.x < nblkA) {
        __shared__ int h[BKN];
        h[t] = 0;
        __syncthreads();
        int base = blockIdx.x * EPB;
        int end = min(base + EPB, E);
        for (int i = base + t; i < end; i += 256) atomicAdd(&h[dst[i] >> BSH], 1);
        __syncthreads();
        for (int i = t; i < NB; i += 256) hist[i * nblkA + blockIdx.x] = h[i];
    } else {
        int blk = blockIdx.x - nblkA;
        const float* W; unsigned short* Wp; int ncols, ct;
        if (blk < 8)       { W = W1; Wp = Wp1; ncols = FDIM; ct = blk; }
        else if (blk < 16) { W = W2; Wp = Wp2; ncols = FDIM; ct = blk - 8; }
        else               { W = Wc; Wp = Wpc; ncols = FCLS; ct = blk - 16; }
        int tt = ct * 256 + t;
        int lane = tt & 63, ks = (tt >> 6) & 3;
        int n  = ct * 16 + (lane & 15);
        int kb = ks * 32 + (lane >> 4) * 8;
        unsigned short v[8];
#pragma unroll
        for (int j = 0; j < 8; ++j) {
            v[j] = (n < ncols) ? f2bf(W[(size_t)(kb + j) * ncols + n]) : (unsigned short)0;
        }
        ushort4* o = (ushort4*)(Wp + (size_t)tt * 8);
        o[0] = ushort4{v[0], v[1], v[2], v[3]};
        o[1] = ushort4{v[4], v[5], v[6], v[7]};
    }
}

// ---- hierarchical exclusive scan of hist[n] (in-place), 1024 elems/block ----
__global__ __launch_bounds__(256) void hscan_partial(const int* __restrict__ data,
                                                     int* __restrict__ bsums, int n) {
    __shared__ int s[256];
    int t = threadIdx.x;
    int base = blockIdx.x * 1024 + t * 4;
    int v = 0;
#pragma unroll
    for (int j = 0; j < 4; ++j) if (base + j < n) v += data[base + j];
    s[t] = v;
    __syncthreads();
    for (int off = 128; off > 0; off >>= 1) {
        if (t < off) s[t] += s[t + off];
        __syncthreads();
    }
    if (t == 0) bsums[blockIdx.x] = s[0];
}

// final scan; each block derives its own base by reducing bsums[0..blockIdx)
__global__ __launch_bounds__(256) void hscan_final(int* __restrict__ data,
                                                   const int* __restrict__ bsums,
                                                   int n, int nb) {
    __shared__ int s[256];
    int t = threadIdx.x;
    s[t] = (t < nb && t < (int)blockIdx.x) ? bsums[t] : 0;
    __syncthreads();
    for (int off = 128; off > 0; off >>= 1) {
        if (t < off) s[t] += s[t + off];
        __syncthreads();
    }
    int base = s[0];
    __syncthreads();

    int idx = blockIdx.x * 1024 + t * 4;
    int v[4];
    int sum = 0;
#pragma unroll
    for (int j = 0; j < 4; ++j) {
        v[j] = (idx + j < n) ? data[idx + j] : 0;
        sum += v[j];
    }
    s[t] = sum;
    __syncthreads();
    for (int off = 1; off < 256; off <<= 1) {
        int x = 0;
        if (t >= off) x = s[t - off];
        __syncthreads();
        s[t] += x;
        __syncthreads();
    }
    int running = base + s[t] - sum;                 // exclusive prefix
#pragma unroll
    for (int j = 0; j < 4; ++j) {
        if (idx + j < n) data[idx + j] = running;
        running += v[j];
    }
}

// ---------------------------------------------------------------------------
// Fused: blocks [0,nblkA) = bin_scatter (CSR critical path);
//        blocks [nblkA, nblkA+gemmBlocks) = layer-1 GEMM (independent work,
//        runs concurrently, hiding it off the critical path).
// ---------------------------------------------------------------------------
__global__ __launch_bounds__(256) void binscatter_gemm1(const int* __restrict__ src,
                                                        const int* __restrict__ dst,
                                                        const int* __restrict__ histS,
                                                        unsigned int* __restrict__ binnedPk,
                                                        int E, int nblkA, int NB,
                                                        const float* __restrict__ A,
                                                        const unsigned short* __restrict__ Wp,
                                                        unsigned short* __restrict__ C, int M) {
    int t = threadIdx.x;
    if ((int)blockIdx.x < nblkA) {
        // ---- bin_scatter part ----
        __shared__ int cur[BKN];
        for (int i = t; i < NB; i += 256) cur[i] = histS[i * nblkA + blockIdx.x];
        __syncthreads();
        int base = blockIdx.x * EPB;
        int end = min(base + EPB, E);
        for (int i = base + t; i < end; i += 256) {
            int d = dst[i];
            int pos = atomicAdd(&cur[d >> BSH], 1);     // LDS atomic
            binnedPk[pos] = (unsigned int)(src[i] & 0xFFFF) | ((unsigned int)d << 16);
        }
    } else {
        // ---- layer-1 GEMM part: C(quarter-blocked bf16) = A(f32) @ Wp ----
        int wave = t >> 6;
        int lane = t & 63;
        int row0 = (((int)blockIdx.x - nblkA) * 4 + wave) * 16;
        if (row0 >= M) return;
        int m = lane & 15;
        int g = lane >> 4;

        const float4* Arow = (const float4*)(A + (size_t)(row0 + m) * FDIM);
        s16x8 a[4];
#pragma unroll
        for (int ks = 0; ks < 4; ++ks) {
            float4 lo = Arow[ks * 8 + g * 2];
            float4 hi = Arow[ks * 8 + g * 2 + 1];
            s16x8 av;
            av[0] = (short)f2bf(lo.x); av[1] = (short)f2bf(lo.y);
            av[2] = (short)f2bf(lo.z); av[3] = (short)f2bf(lo.w);
            av[4] = (short)f2bf(hi.x); av[5] = (short)f2bf(hi.y);
            av[6] = (short)f2bf(hi.z); av[7] = (short)f2bf(hi.w);
            a[ks] = av;
        }

        for (int ct = 0; ct < 8; ++ct) {
            f32x4 acc = {0.f, 0.f, 0.f, 0.f};
#pragma unroll
            for (int ks = 0; ks < 4; ++ks) {
                s16x8 b = *(const s16x8*)(Wp + ((size_t)((ct * 4 + ks) * 64 + lane)) * 8);
                acc = __builtin_amdgcn_mfma_f32_16x16x32_bf16(a[ks], b, acc, 0, 0, 0);
            }
            int q  = ct >> 1;
            int cc = (ct & 1) * 16 + m;
            int r0 = row0 + g * 4;
#pragma unroll
            for (int r = 0; r < 4; ++r)
                C[((size_t)q * M + (r0 + r)) * 32 + cc] = f2bf(acc[r]);
        }
    }
}

// per-bucket node histogram + in-LDS exclusive scan -> offsets, dinv
__global__ __launch_bounds__(256) void node_hist_scan(const unsigned int* __restrict__ binnedPk,
                                                      const int* __restrict__ histS,
                                                      int* __restrict__ offsets,
                                                      float* __restrict__ dinv,
                                                      int N, int E, int nblkA, int NB) {
    int b = blockIdx.x;
    int node0 = b << BSH;
    int t = threadIdx.x;
    __shared__ int c[BKN];
    c[t] = 0;
    __syncthreads();
    int lo = histS[b * nblkA];
    int hi = (b == NB - 1) ? E : histS[(b + 1) * nblkA];
    for (int i = lo + t; i < hi; i += 256) {
        int d = (int)(binnedPk[i] >> 16);
        atomicAdd(&c[d - node0], 1);                // LDS atomic
    }
    __syncthreads();
    int v = c[t];
    for (int off = 1; off < 256; off <<= 1) {
        int x = (t >= off) ? c[t - off] : 0;
        __syncthreads();
        c[t] += x;
        __syncthreads();
    }
    int excl = lo + c[t] - v;                       // bucket base + exclusive prefix
    int idx = node0 + t;
    if (idx < N) {
        offsets[idx] = excl;
        dinv[idx] = rsqrtf((float)v + 1.0f);
        if (idx == N - 1) offsets[N] = excl + v;    // == E
    }
}

// per-bucket exact positions; writes srcPk = src | fp16(dinv[s]*dinv[d])<<16
__global__ __launch_bounds__(256) void csr_scatter(const unsigned int* __restrict__ binnedPk,
                                                   const int* __restrict__ offsets,
                                                   const float* __restrict__ dinv,
                                                   unsigned int* __restrict__ srcPk, int N) {
    int b = blockIdx.x;
    int node0 = b << BSH;
    int node1 = min(node0 + BKN, N);
    __shared__ int cur[BKN];
    int t = threadIdx.x;
    if (node0 + t < node1) cur[t] = offsets[node0 + t];
    __syncthreads();
    int lo = offsets[node0];
    int hi = offsets[node1];
    for (int i = lo + t; i < hi; i += 256) {
        unsigned int p = binnedPk[i];
        int s = (int)(p & 0xFFFFu);
        int d = (int)(p >> 16);
        int pos = atomicAdd(&cur[d - node0], 1);    // LDS atomic
        float coef = dinv[s] * dinv[d];
        unsigned short cb = __half_as_ushort(__float2half(coef));
        srcPk[pos] = (unsigned int)s | ((unsigned int)cb << 16);
    }
}

// ---------------------------------------------------------------------------
// Quarter-blocked bf16 layout: buf[q][node][32 cols], q = col/32.
// ---------------------------------------------------------------------------

// quarter-blocked bf16 A variant (layer 2)
__global__ __launch_bounds__(256) void gemm_mfma(const unsigned short* __restrict__ A,
                                                 const unsigned short* __restrict__ Wp,
                                                 unsigned short* __restrict__ C, int M) {
    int wave = threadIdx.x >> 6;
    int lane = threadIdx.x & 63;
    int row0 = (blockIdx.x * 4 + wave) * 16;
    if (row0 >= M) return;
    int m = lane & 15;
    int g = lane >> 4;

    const s16x8* A8 = (const s16x8*)A;
    s16x8 a[4];
#pragma unroll
    for (int ks = 0; ks < 4; ++ks)
        a[ks] = A8[((size_t)ks * M + (row0 + m)) * 4 + g];

    for (int ct = 0; ct < 8; ++ct) {
        f32x4 acc = {0.f, 0.f, 0.f, 0.f};
#pragma unroll
        for (int ks = 0; ks < 4; ++ks) {
            s16x8 b = *(const s16x8*)(Wp + ((size_t)((ct * 4 + ks) * 64 + lane)) * 8);
            acc = __builtin_amdgcn_mfma_f32_16x16x32_bf16(a[ks], b, acc, 0, 0, 0);
        }
        int q  = ct >> 1;
        int cc = (ct & 1) * 16 + m;
        int r0 = row0 + g * 4;
#pragma unroll
        for (int r = 0; r < 4; ++r)
            C[((size_t)q * M + (r0 + r)) * 32 + cc] = f2bf(acc[r]);
    }
}

// out[M,40](f32) = A(quarter-blocked bf16) @ Wc(packed, zero-padded) + bc
__global__ __launch_bounds__(256) void classifier_mfma(const unsigned short* __restrict__ A,
                                                       const unsigned short* __restrict__ Wp,
                                                       const float* __restrict__ bc,
                                                       float* __restrict__ out, int M) {
    int wave = threadIdx.x >> 6;
    int lane = threadIdx.x & 63;
    int row0 = (blockIdx.x * 4 + wave) * 16;
    if (row0 >= M) return;
    int m = lane & 15;
    int g = lane >> 4;

    const s16x8* A8 = (const s16x8*)A;
    s16x8 a[4];
#pragma unroll
    for (int ks = 0; ks < 4; ++ks)
        a[ks] = A8[((size_t)ks * M + (row0 + m)) * 4 + g];

    for (int ct = 0; ct < 3; ++ct) {
        f32x4 acc = {0.f, 0.f, 0.f, 0.f};
#pragma unroll
        for (int ks = 0; ks < 4; ++ks) {
            s16x8 b = *(const s16x8*)(Wp + ((size_t)((ct * 4 + ks) * 64 + lane)) * 8);
            acc = __builtin_amdgcn_mfma_f32_16x16x32_bf16(a[ks], b, acc, 0, 0, 0);
        }
        int n = ct * 16 + m;
        if (n < FCLS) {
            float bias = bc[n];
            int r0 = row0 + g * 4;
#pragma unroll
            for (int r = 0; r < 4; ++r)
                out[(size_t)(r0 + r) * FCLS + n] = acc[r] + bias;
        }
    }
}

// ---------------------------------------------------------------------------
// Fused aggregation over quarter-blocked H with XCD-pinned quarters and
// LDS-staged metadata. Inner loop software-pipelined depth 6.
// ---------------------------------------------------------------------------
__global__ __launch_bounds__(256) void agg_fused(const unsigned short* __restrict__ H,
                                                 const float* __restrict__ dinv,
                                                 const float* __restrict__ bias,
                                                 const unsigned int* __restrict__ srcPk,
                                                 const int* __restrict__ offsets,
                                                 unsigned short* __restrict__ OUT,
                                                 int N, int bpq) {
    __shared__ unsigned int eLds[LCAP];
    int gid = blockIdx.x;
    int q = (gid >> 1) & 3;                        // (gid % 8) >> 1
    int b = (gid >> 3) * 2 + (gid & 1);            // within-quarter block
    int t = threadIdx.x;
    int nodeB = b * 64;
    int nodeE = min(nodeB + 64, N);
    int node = nodeB + (t >> 2);
    bool valid = node < N;
    int c4 = t & 3;

    int lo  = offsets[nodeB];
    int cnt = offsets[nodeE] - lo;
    int stg = min(cnt, LCAP);
    for (int i = t; i < stg; i += 256) eLds[i] = srcPk[lo + i];
    __syncthreads();

    const s16x8* H8 = (const s16x8*)H;             // quarter-row = 4 s16x8
    size_t qbase = (size_t)q * N * 4;

    float di = 0.f, d2 = 0.f;
    int e = 0, end = 0;
    float acc[8];
#pragma unroll
    for (int j = 0; j < 8; ++j) acc[j] = 0.f;
    if (valid) {
        di = dinv[node];
        d2 = di * di;
        e   = offsets[node] - lo;
        end = offsets[node + 1] - lo;
        s16x8 h = H8[qbase + (size_t)node * 4 + c4];
#pragma unroll
        for (int j = 0; j < 8; ++j) acc[j] = bf2f((unsigned short)h[j]) * d2;
    }

    if (cnt <= LCAP) {
        if (valid) {
            if (e + 6 <= end) {
                unsigned int p[6];
#pragma unroll
                for (int k = 0; k < 6; ++k) p[k] = eLds[e + k];
                while (e + 12 <= end) {
                    s16x8 av[6];
#pragma unroll
                    for (int k = 0; k < 6; ++k)
                        av[k] = H8[qbase + (size_t)(p[k] & 0xFFFFu) * 4 + c4];
                    unsigned int pn[6];
#pragma unroll
                    for (int k = 0; k < 6; ++k) pn[k] = eLds[e + 6 + k];
#pragma unroll
                    for (int k = 0; k < 6; ++k) {
                        float cf = __half2float(__ushort_as_half((unsigned short)(p[k] >> 16)));
#pragma unroll
                        for (int j = 0; j < 8; ++j)
                            acc[j] = fmaf(bf2f((unsigned short)av[k][j]), cf, acc[j]);
                    }
#pragma unroll
                    for (int k = 0; k < 6; ++k) p[k] = pn[k];
                    e += 6;
                }
                s16x8 av[6];
#pragma unroll
                for (int k = 0; k < 6; ++k)
                    av[k] = H8[qbase + (size_t)(p[k] & 0xFFFFu) * 4 + c4];
#pragma unroll
                for (int k = 0; k < 6; ++k) {
                    float cf = __half2float(__ushort_as_half((unsigned short)(p[k] >> 16)));
#pragma unroll
                    for (int j = 0; j < 8; ++j)
                        acc[j] = fmaf(bf2f((unsigned short)av[k][j]), cf, acc[j]);
                }
                e += 6;
            }
            for (; e + 2 <= end; e += 2) {
                unsigned int p0 = eLds[e], p1 = eLds[e + 1];
                s16x8 a0 = H8[qbase + (size_t)(p0 & 0xFFFFu) * 4 + c4];
                s16x8 a1 = H8[qbase + (size_t)(p1 & 0xFFFFu) * 4 + c4];
                float c0 = __half2float(__ushort_as_half((unsigned short)(p0 >> 16)));
                float c1 = __half2float(__ushort_as_half((unsigned short)(p1 >> 16)));
#pragma unroll
                for (int j = 0; j < 8; ++j) {
                    acc[j] = fmaf(bf2f((unsigned short)a0[j]), c0, acc[j]);
                    acc[j] = fmaf(bf2f((unsigned short)a1[j]), c1, acc[j]);
                }
            }
            if (e < end) {
                unsigned int p0 = eLds[e];
                float c0 = __half2float(__ushort_as_half((unsigned short)(p0 >> 16)));
                s16x8 a0 = H8[qbase + (size_t)(p0 & 0xFFFFu) * 4 + c4];
#pragma unroll
                for (int j = 0; j < 8; ++j)
                    acc[j] = fmaf(bf2f((unsigned short)a0[j]), c0, acc[j]);
            }
        }
    } else {
        if (valid) {
            for (; e + 6 <= end; e += 6) {
                unsigned int p[6];
#pragma unroll
                for (int k = 0; k < 6; ++k) p[k] = srcPk[lo + e + k];
                s16x8 av[6];
#pragma unroll
                for (int k = 0; k < 6; ++k)
                    av[k] = H8[qbase + (size_t)(p[k] & 0xFFFFu) * 4 + c4];
#pragma unroll
                for (int k = 0; k < 6; ++k) {
                    float cf = __half2float(__ushort_as_half((unsigned short)(p[k] >> 16)));
#pragma unroll
                    for (int j = 0; j < 8; ++j)
                        acc[j] = fmaf(bf2f((unsigned short)av[k][j]), cf, acc[j]);
                }
            }
            for (; e < end; ++e) {
                unsigned int p0 = srcPk[lo + e];
                float c0 = __half2float(__ushort_as_half((unsigned short)(p0 >> 16)));
                s16x8 a0 = H8[qbase + (size_t)(p0 & 0xFFFFu) * 4 + c4];
#pragma unroll
                for (int j = 0; j < 8; ++j)
                    acc[j] = fmaf(bf2f((unsigned short)a0[j]), c0, acc[j]);
            }
        }
    }

    if (valid) {
        const float4* bq = (const float4*)(bias + q * 32 + c4 * 8);
        float4 b0 = bq[0], b1 = bq[1];
        float bb[8] = {b0.x, b0.y, b0.z, b0.w, b1.x, b1.y, b1.z, b1.w};
        s16x8 o;
#pragma unroll
        for (int j = 0; j < 8; ++j)
            o[j] = (short)f2bf(fmaxf(acc[j] + bb[j], 0.0f));
        ((s16x8*)OUT)[qbase + (size_t)node * 4 + c4] = o;
    }
}

// ---------------------------------------------------------------------------
extern "C" void kernel_launch(void* const* d_in, const int* in_sizes, int n_in,
                              void* d_out, int out_size, void* d_ws, size_t ws_size,
                              hipStream_t stream) {
    const float* x  = (const float*)d_in[0];
    const int*   ei = (const int*)d_in[1];
    const float* W1 = (const float*)d_in[2];
    const float* b1 = (const float*)d_in[3];
    const float* W2 = (const float*)d_in[4];
    const float* b2 = (const float*)d_in[5];
    const float* Wc = (const float*)d_in[6];
    const float* bc = (const float*)d_in[7];
    float* out = (float*)d_out;

    int N = in_sizes[0] / FDIM;
    int E = in_sizes[1] / 2;
    const int* src = ei;
    const int* dst = ei + E;

    int nblkA = (E + EPB - 1) / EPB;            // 196
    int NB    = (N + BKN - 1) >> BSH;           // 196
    int mfmaBlocks = (N / 16 + 3) / 4;          // 782
    int bpq = (N + 63) / 64;                    // 782 blocks per quarter
    int aggBlocks = 4 * bpq;                    // 3128 (divisible by 8)
    int histN = NB * nblkA;                     // 38416
    int hscanBlocks = (histN + 1023) / 1024;    // 38 (<= 256 required)

    // workspace layout:
    // binnedPk[E] | srcPk[E] | offsets[N+1] | hist[histN] | bsums[256]
    // | dinv[N] | Wp1 | Wp2 | Wpc | Hbuf bf16 | Abuf bf16
    unsigned int* binnedPk = (unsigned int*)d_ws;
    unsigned int* srcPk    = binnedPk + E;
    int*  offsets  = (int*)(srcPk + E);
    int*  hist     = offsets + (N + 1);
    int*  bsums    = hist + histN;
    float* dinv    = (float*)(bsums + 256);
    unsigned short* Wp1 = (unsigned short*)(dinv + N);
    unsigned short* Wp2 = Wp1 + 8 * 4 * 64 * 8;
    unsigned short* Wpc = Wp2 + 8 * 4 * 64 * 8;
    unsigned short* Hbuf = Wpc + 3 * 4 * 64 * 8;
    unsigned short* Abuf = Hbuf + (size_t)N * FDIM;

    // ---- prep: bucket histogram + weight packing (1 fused dispatch) ----
    prep_hist_pack<<<nblkA + 19, 256, 0, stream>>>(dst, hist, E, nblkA, NB,
                                                   W1, W2, Wc, Wp1, Wp2, Wpc);
    // ---- CSR build (gemm1 fused into bin_scatter dispatch, off-path) ----
    hscan_partial<<<hscanBlocks, 256, 0, stream>>>(hist, bsums, histN);
    hscan_final<<<hscanBlocks, 256, 0, stream>>>(hist, bsums, histN, hscanBlocks);
    binscatter_gemm1<<<nblkA + mfmaBlocks, 256, 0, stream>>>(src, dst, hist, binnedPk,
                                                             E, nblkA, NB,
                                                             x, Wp1, Hbuf, N);
    node_hist_scan<<<NB, 256, 0, stream>>>(binnedPk, hist, offsets, dinv, N, E, nblkA, NB);
    csr_scatter<<<NB, 256, 0, stream>>>(binnedPk, offsets, dinv, srcPk, N);

    // ---- layer 1 aggregation ----
    agg_fused<<<aggBlocks, 256, 0, stream>>>(Hbuf, dinv, b1, srcPk, offsets, Abuf, N, bpq);

    // ---- layer 2 ----
    gemm_mfma<<<mfmaBlocks, 256, 0, stream>>>(Abuf, Wp2, Hbuf, N);
    agg_fused<<<aggBlocks, 256, 0, stream>>>(Hbuf, dinv, b2, srcPk, offsets, Abuf, N, bpq);

    // ---- classifier ----
    classifier_mfma<<<mfmaBlocks, 256, 0, stream>>>(Abuf, Wpc, bc, out, N);
}